// Round 5
// baseline (836.880 us; speedup 1.0000x reference)
//
#include <hip/hip_runtime.h>

// ---------------------------------------------------------------------------
// EnhancedSparseAttention (fp32 I/O): x:(1,256,64,64) f32,
// mask:(1,8,4096,4096) int32, weights f32. Output f32 (1,256,64,64).
// R5: flash split-K x4 (8 blocks/CU -> 32 waves/CU max occupancy) to hide
//     HBM latency on the mask/K/V streams; outln merges 4 partials.
//     NOTE: dur_us includes ~650-700us fixed harness reset overhead (2.1GB
//     ws poison fill ~330us + 540MB input restore); kernel share ~150us.
// ---------------------------------------------------------------------------

#define NH 8
#define CC 256
#define NN 4096
#define HD 32
#define KSPLIT 4

typedef short bf16x8 __attribute__((ext_vector_type(8)));
typedef float f32x4 __attribute__((ext_vector_type(4)));
typedef float float4v __attribute__((ext_vector_type(4)));

__device__ __forceinline__ unsigned short f2bf(float f) {
    union { float f; unsigned int i; } v;
    v.f = f;
    unsigned int i = v.i;
    i += 0x7FFFu + ((i >> 16) & 1u);   // round-to-nearest-even
    return (unsigned short)(i >> 16);
}

// ---------------------------------------------------------------------------
// Kernel 1: QKV projection.  y[o][n] = sum_c W[o][c] x[c][n] + b[o]
// blockIdx.y in {0,1,2} selects Q/K/V.  n-tile = 32 pixels, thread = o.
// Q,K stored bf16 [h][n][d]; V stored bf16 transposed [o][n].
// ---------------------------------------------------------------------------
__global__ __launch_bounds__(256) void proj_kernel(
    const float* __restrict__ x,
    const float* __restrict__ Wq, const float* __restrict__ bq,
    const float* __restrict__ Wk, const float* __restrict__ bk,
    const float* __restrict__ Wv, const float* __restrict__ bv,
    unsigned short* __restrict__ Qb,
    unsigned short* __restrict__ Kb,
    unsigned short* __restrict__ Vtb)
{
    const int t = threadIdx.x;
    const int which = blockIdx.y;
    const int n0 = blockIdx.x * 32;

    const float* W    = (which == 0) ? Wq : (which == 1) ? Wk : Wv;
    const float* bias = (which == 0) ? bq : (which == 1) ? bk : bv;

    __shared__ float xs[CC][36];
    {
        const float* xr = x + (size_t)t * NN + n0;
        #pragma unroll
        for (int g = 0; g < 8; ++g)
            *(float4v*)&xs[t][g * 4] = *(const float4v*)(xr + g * 4);
    }
    __syncthreads();

    float acc[32];
    #pragma unroll
    for (int i = 0; i < 32; ++i) acc[i] = 0.f;

    const float4v* w4p = (const float4v*)(W + (size_t)t * CC);
    for (int cg = 0; cg < 64; ++cg) {
        float4v w4 = w4p[cg];
        #pragma unroll
        for (int k = 0; k < 4; ++k) {
            const float w = w4[k];
            const float* xr = &xs[cg * 4 + k][0];
            #pragma unroll
            for (int g = 0; g < 8; ++g) {
                float4v xv = *(const float4v*)(xr + g * 4);
                acc[g * 4 + 0] = fmaf(w, xv[0], acc[g * 4 + 0]);
                acc[g * 4 + 1] = fmaf(w, xv[1], acc[g * 4 + 1]);
                acc[g * 4 + 2] = fmaf(w, xv[2], acc[g * 4 + 2]);
                acc[g * 4 + 3] = fmaf(w, xv[3], acc[g * 4 + 3]);
            }
        }
    }

    const float b = bias[t];
    if (which < 2) {
        unsigned short* dst = (which == 0) ? Qb : Kb;
        const int h = t >> 5, d = t & 31;
        #pragma unroll
        for (int n = 0; n < 32; ++n)
            dst[((size_t)(h * NN + n0 + n)) * HD + d] = f2bf(acc[n] + b);
    } else {
        unsigned short* dst = Vtb + (size_t)t * NN + n0;
        #pragma unroll
        for (int g = 0; g < 4; ++g) {
            unsigned short v[8];
            #pragma unroll
            for (int k = 0; k < 8; ++k) v[k] = f2bf(acc[g * 8 + k] + b);
            *(bf16x8*)(void*)(dst + g * 8) = *(const bf16x8*)(const void*)v;
        }
    }
}

// ---------------------------------------------------------------------------
// Kernel 2: flash attention, fixed-max softmax, split-K x4.
// grid = (64 q-tiles, 8 heads, 4 k-splits); block = 256 thr = 4 waves.
// Wave owns 16 q-rows; per 32-key j-tile: 2 S-MFMAs, p=exp2(s-M) (no max
// tracking), P->LDS->A-frag (per-wave waitcnt), 2 PV-MFMAs.
// Emits UNNORMALIZED O-partial att[ks][o][n] and l-partial lp[ks][h][n].
// ---------------------------------------------------------------------------
__global__ __launch_bounds__(256) void flash_kernel(
    const unsigned short* __restrict__ Q,
    const unsigned short* __restrict__ K,
    const unsigned short* __restrict__ Vt,
    const int* __restrict__ mask,
    float* __restrict__ att,
    float* __restrict__ lp)
{
    const int tid  = threadIdx.x;
    const int wave = tid >> 6;
    const int lane = tid & 63;
    const int quad = lane >> 4;
    const int l16  = lane & 15;
    const int h    = blockIdx.y;
    const int ks   = blockIdx.z;
    const int q0   = blockIdx.x * 64 + wave * 16;

    float* attp = att + (size_t)ks * CC * NN;
    float* lpp  = lp  + (size_t)ks * NH * NN;

    // per-wave P buffer: 16 rows x 40 shorts (80B rows, 16B-aligned)
    __shared__ __align__(16) unsigned short plds[4][16 * 40];
    unsigned short* pw = plds[wave];

    // Q A-fragment: A[m=l16][k=quad*8+j]
    const bf16x8 aq =
        *(const bf16x8*)(const void*)(Q + ((size_t)(h * NN + q0 + l16)) * HD + quad * 8);

    const unsigned short* kbase = K + (size_t)h * NN * HD;
    const unsigned short* vb0p  = Vt + ((size_t)(h * HD + l16)) * NN;   // d = l16
    const unsigned short* vb1p  = vb0p + (size_t)16 * NN;               // d = 16+l16

    const int* mrow[4];
    #pragma unroll
    for (int r = 0; r < 4; ++r)
        mrow[r] = mask + ((size_t)(h * NN + q0 + quad * 4 + r)) * NN + l16;

    f32x4 O0 = {0.f, 0.f, 0.f, 0.f};
    f32x4 O1 = {0.f, 0.f, 0.f, 0.f};
    float l_[4] = {0.f, 0.f, 0.f, 0.f};

    // p = exp2(s*scale*log2e - M*log2e); M=8 (scores ~N(0,1), max ~5.7)
    const float cs = 0.25503372600239960f;   // (1/sqrt(32)) * log2(e)
    const float c8 = 11.541560327111707f;    // 8 * log2(e)
    const f32x4 zero4 = {0.f, 0.f, 0.f, 0.f};

    const int kbeg = ks * (NN / KSPLIT);
    const int kend = kbeg + (NN / KSPLIT);

    #pragma unroll 2
    for (int j0 = kbeg; j0 < kend; j0 += 32) {
        // K B-frags: lane reads K[j0+l16][quad*8..+8] (wave covers 1KB contig)
        bf16x8 bk0 = *(const bf16x8*)(const void*)(kbase + (size_t)(j0 + l16) * HD + quad * 8);
        bf16x8 bk1 = *(const bf16x8*)(const void*)(kbase + (size_t)(j0 + 16 + l16) * HD + quad * 8);
        // V B-frags: lane reads Vt[d][j0+quad*8..+8]
        bf16x8 bv0 = *(const bf16x8*)(const void*)(vb0p + j0 + quad * 8);
        bf16x8 bv1 = *(const bf16x8*)(const void*)(vb1p + j0 + quad * 8);
        // mask: 8 coalesced dwords/lane-iter (64B per quad-row)
        int mk0[4], mk1[4];
        #pragma unroll
        for (int r = 0; r < 4; ++r) { mk0[r] = mrow[r][j0]; mk1[r] = mrow[r][j0 + 16]; }

        f32x4 S0 = __builtin_amdgcn_mfma_f32_16x16x32_bf16(aq, bk0, zero4, 0, 0, 0);
        f32x4 S1 = __builtin_amdgcn_mfma_f32_16x16x32_bf16(aq, bk1, zero4, 0, 0, 0);

        #pragma unroll
        for (int r = 0; r < 4; ++r) {
            float t0 = S0[r] * cs - c8;  if (!mk0[r]) t0 = -1e38f;
            float t1 = S1[r] * cs - c8;  if (!mk1[r]) t1 = -1e38f;
            const float p0 = exp2f(t0);   // masked -> exactly 0
            const float p1 = exp2f(t1);
            l_[r] += p0 + p1;
            // C/D layout: row = quad*4+r, col = l16 (frag0) / 16+l16 (frag1)
            pw[(quad * 4 + r) * 40 + l16]      = f2bf(p0);
            pw[(quad * 4 + r) * 40 + 16 + l16] = f2bf(p1);
        }

        // same-wave LDS RAW: drain this wave's ds_writes before A-frag read
        __asm__ volatile("s_waitcnt lgkmcnt(0)" ::: "memory");
        bf16x8 ap = *(const bf16x8*)(const void*)(pw + l16 * 40 + quad * 8);

        O0 = __builtin_amdgcn_mfma_f32_16x16x32_bf16(ap, bv0, O0, 0, 0, 0);
        O1 = __builtin_amdgcn_mfma_f32_16x16x32_bf16(ap, bv1, O1, 0, 0, 0);
        // cross-iter WAR is same-wave only (per-wave buffer): DS in-order.
    }

    // deferred l reduction: sum across the 16 lanes of each quad group
    #pragma unroll
    for (int r = 0; r < 4; ++r) {
        float l = l_[r];
        l += __shfl_xor(l, 1);
        l += __shfl_xor(l, 2);
        l += __shfl_xor(l, 4);
        l += __shfl_xor(l, 8);
        const int n = q0 + quad * 4 + r;
        attp[(size_t)(h * HD + l16) * NN + n]      = O0[r];
        attp[(size_t)(h * HD + 16 + l16) * NN + n] = O1[r];
        if (l16 == 0) lpp[h * NN + n] = l;
    }
}

// ---------------------------------------------------------------------------
// Kernel 3: combine split-K partials, out = Wo@att + bo; z = x + out;
// channel LayerNorm per pixel. grid = 256 x 16-pixel tiles; thread = channel.
// ---------------------------------------------------------------------------
__global__ __launch_bounds__(256) void outln_kernel(
    const float* __restrict__ att,
    const float* __restrict__ lp,
    const float* __restrict__ x,
    const float* __restrict__ Wo,
    const float* __restrict__ bo,
    const float* __restrict__ gamma,
    const float* __restrict__ beta,
    float* __restrict__ out)
{
    const int t  = threadIdx.x;
    const int n0 = blockIdx.x * 16;

    __shared__ float as_[CC][20];
    __shared__ float red[2][16][16];
    __shared__ float mus[16], rstds[16];
    __shared__ float linv[NH][16];

    if (t < NH * 16) {
        const int h = t >> 4, nl = t & 15;
        float L = 0.f;
        #pragma unroll
        for (int s = 0; s < KSPLIT; ++s)
            L += lp[(size_t)s * NH * NN + h * NN + n0 + nl];
        linv[h][nl] = 1.f / fmaxf(L, 1e-20f);
    }
    __syncthreads();

    {
        const int h = t >> 5;
        #pragma unroll
        for (int g = 0; g < 4; ++g) {
            float4v v = {0.f, 0.f, 0.f, 0.f};
            #pragma unroll
            for (int s = 0; s < KSPLIT; ++s) {
                float4v vs = *(const float4v*)(att + (size_t)s * CC * NN
                                               + (size_t)t * NN + n0 + g * 4);
                v[0] += vs[0]; v[1] += vs[1]; v[2] += vs[2]; v[3] += vs[3];
            }
            v[0] *= linv[h][g * 4 + 0];
            v[1] *= linv[h][g * 4 + 1];
            v[2] *= linv[h][g * 4 + 2];
            v[3] *= linv[h][g * 4 + 3];
            *(float4v*)&as_[t][g * 4] = v;
        }
    }
    __syncthreads();

    float acc[16];
    #pragma unroll
    for (int i = 0; i < 16; ++i) acc[i] = 0.f;

    const float4v* w4p = (const float4v*)(Wo + (size_t)t * CC);
    for (int cg = 0; cg < 64; ++cg) {
        float4v w4 = w4p[cg];
        #pragma unroll
        for (int k = 0; k < 4; ++k) {
            const float w = w4[k];
            const float* xr = &as_[cg * 4 + k][0];
            #pragma unroll
            for (int g = 0; g < 4; ++g) {
                float4v xv = *(const float4v*)(xr + g * 4);
                acc[g * 4 + 0] = fmaf(w, xv[0], acc[g * 4 + 0]);
                acc[g * 4 + 1] = fmaf(w, xv[1], acc[g * 4 + 1]);
                acc[g * 4 + 2] = fmaf(w, xv[2], acc[g * 4 + 2]);
                acc[g * 4 + 3] = fmaf(w, xv[3], acc[g * 4 + 3]);
            }
        }
    }

    {
        const float b = bo[t];
        const float* xr = x + (size_t)t * NN + n0;
        #pragma unroll
        for (int g = 0; g < 4; ++g) {
            float4v xv = *(const float4v*)(xr + g * 4);
            acc[g * 4 + 0] += b + xv[0];
            acc[g * 4 + 1] += b + xv[1];
            acc[g * 4 + 2] += b + xv[2];
            acc[g * 4 + 3] += b + xv[3];
        }
    }

    __syncthreads();
    #pragma unroll
    for (int g = 0; g < 4; ++g) {
        float4v v = {acc[g * 4 + 0], acc[g * 4 + 1], acc[g * 4 + 2], acc[g * 4 + 3]};
        *(float4v*)&as_[t][g * 4] = v;
    }
    __syncthreads();

    {
        const int part = t >> 4, p = t & 15;
        float sm = 0.f, sq = 0.f;
        #pragma unroll
        for (int s = 0; s < 16; ++s) {
            float z = as_[part * 16 + s][p];
            sm += z;
            sq = fmaf(z, z, sq);
        }
        red[0][part][p] = sm;
        red[1][part][p] = sq;
    }
    __syncthreads();
    if (t < 16) {
        float S = 0.f, Q2 = 0.f;
        #pragma unroll
        for (int s = 0; s < 16; ++s) { S += red[0][s][t]; Q2 += red[1][s][t]; }
        const float mu  = S * (1.f / 256.f);
        const float var = Q2 * (1.f / 256.f) - mu * mu;
        mus[t]   = mu;
        rstds[t] = rsqrtf(fmaxf(var, 0.f) + 1e-5f);
    }
    __syncthreads();

    const float g_ = gamma[t];
    const float be = beta[t];
    float* dst = out + (size_t)t * NN + n0;
    #pragma unroll
    for (int g = 0; g < 4; ++g) {
        float4v v;
        v[0] = (acc[g * 4 + 0] - mus[g * 4 + 0]) * rstds[g * 4 + 0] * g_ + be;
        v[1] = (acc[g * 4 + 1] - mus[g * 4 + 1]) * rstds[g * 4 + 1] * g_ + be;
        v[2] = (acc[g * 4 + 2] - mus[g * 4 + 2]) * rstds[g * 4 + 2] * g_ + be;
        v[3] = (acc[g * 4 + 3] - mus[g * 4 + 3]) * rstds[g * 4 + 3] * g_ + be;
        *(float4v*)(dst + g * 4) = v;
    }
}

// ---------------------------------------------------------------------------
extern "C" void kernel_launch(void* const* d_in, const int* in_sizes, int n_in,
                              void* d_out, int out_size, void* d_ws, size_t ws_size,
                              hipStream_t stream) {
    const float* x     = (const float*)d_in[0];
    const int*   mask  = (const int*)d_in[1];
    const float* Wq    = (const float*)d_in[2];
    const float* bq    = (const float*)d_in[3];
    const float* Wk    = (const float*)d_in[4];
    const float* bk    = (const float*)d_in[5];
    const float* Wv    = (const float*)d_in[6];
    const float* bv    = (const float*)d_in[7];
    const float* Wo    = (const float*)d_in[8];
    const float* bo    = (const float*)d_in[9];
    const float* gamma = (const float*)d_in[10];
    const float* beta  = (const float*)d_in[11];

    // ws: Qb 2MB | Kb 2MB | Vtb 2MB | att 4x4MB | lp 4x128KB  (~22.5MB)
    char* ws = (char*)d_ws;
    unsigned short* Qb  = (unsigned short*)ws;
    unsigned short* Kb  = Qb + (size_t)NH * NN * HD;
    unsigned short* Vtb = Kb + (size_t)NH * NN * HD;
    float*          att = (float*)(Vtb + (size_t)NH * NN * HD);
    float*          lpt = att + (size_t)KSPLIT * CC * NN;

    proj_kernel<<<dim3(NN / 32, 3), 256, 0, stream>>>(x, Wq, bq, Wk, bk, Wv, bv,
                                                      Qb, Kb, Vtb);
    flash_kernel<<<dim3(NN / 64, NH, KSPLIT), 256, 0, stream>>>(Qb, Kb, Vtb,
                                                                mask, att, lpt);
    outln_kernel<<<dim3(NN / 16), 256, 0, stream>>>(att, lpt, x, Wo, bo,
                                                    gamma, beta, (float*)d_out);
}

// Round 6
// 833.098 us; speedup vs baseline: 1.0045x; 1.0045x over previous
//
#include <hip/hip_runtime.h>

// ---------------------------------------------------------------------------
// EnhancedSparseAttention (fp32 I/O): x:(1,256,64,64) f32,
// mask:(1,8,4096,4096) int32, weights f32. Output f32 (1,256,64,64).
// R6: KSPLIT=2 (R4 best) + bf16 att partials (halve partial HBM traffic).
// Fixed-max softmax (M=8), per-wave lgkmcnt P handshake, 32 waves/CU.
// NOTE: dur_us includes ~685us fixed harness reset (2GiB ws poison fill
// ~335us + 536MB mask restore ~170us); controllable kernel share ~140us,
// of which ~95us is the mask/partial HBM floor.
// ---------------------------------------------------------------------------

#define NH 8
#define CC 256
#define NN 4096
#define HD 32
#define KSPLIT 2

typedef short bf16x8 __attribute__((ext_vector_type(8)));
typedef float f32x4 __attribute__((ext_vector_type(4)));
typedef float float4v __attribute__((ext_vector_type(4)));
typedef unsigned short ushort8 __attribute__((ext_vector_type(8)));

__device__ __forceinline__ float bf2f(unsigned short u) {
    union { unsigned int i; float f; } v;
    v.i = ((unsigned int)u) << 16;
    return v.f;
}
__device__ __forceinline__ unsigned short f2bf(float f) {
    union { float f; unsigned int i; } v;
    v.f = f;
    unsigned int i = v.i;
    i += 0x7FFFu + ((i >> 16) & 1u);   // round-to-nearest-even
    return (unsigned short)(i >> 16);
}

// ---------------------------------------------------------------------------
// Kernel 1: QKV projection.  y[o][n] = sum_c W[o][c] x[c][n] + b[o]
// blockIdx.y in {0,1,2} selects Q/K/V.  n-tile = 32 pixels, thread = o.
// Q,K stored bf16 [h][n][d]; V stored bf16 transposed [o][n].
// ---------------------------------------------------------------------------
__global__ __launch_bounds__(256) void proj_kernel(
    const float* __restrict__ x,
    const float* __restrict__ Wq, const float* __restrict__ bq,
    const float* __restrict__ Wk, const float* __restrict__ bk,
    const float* __restrict__ Wv, const float* __restrict__ bv,
    unsigned short* __restrict__ Qb,
    unsigned short* __restrict__ Kb,
    unsigned short* __restrict__ Vtb)
{
    const int t = threadIdx.x;
    const int which = blockIdx.y;
    const int n0 = blockIdx.x * 32;

    const float* W    = (which == 0) ? Wq : (which == 1) ? Wk : Wv;
    const float* bias = (which == 0) ? bq : (which == 1) ? bk : bv;

    __shared__ float xs[CC][36];
    {
        const float* xr = x + (size_t)t * NN + n0;
        #pragma unroll
        for (int g = 0; g < 8; ++g)
            *(float4v*)&xs[t][g * 4] = *(const float4v*)(xr + g * 4);
    }
    __syncthreads();

    float acc[32];
    #pragma unroll
    for (int i = 0; i < 32; ++i) acc[i] = 0.f;

    const float4v* w4p = (const float4v*)(W + (size_t)t * CC);
    for (int cg = 0; cg < 64; ++cg) {
        float4v w4 = w4p[cg];
        #pragma unroll
        for (int k = 0; k < 4; ++k) {
            const float w = w4[k];
            const float* xr = &xs[cg * 4 + k][0];
            #pragma unroll
            for (int g = 0; g < 8; ++g) {
                float4v xv = *(const float4v*)(xr + g * 4);
                acc[g * 4 + 0] = fmaf(w, xv[0], acc[g * 4 + 0]);
                acc[g * 4 + 1] = fmaf(w, xv[1], acc[g * 4 + 1]);
                acc[g * 4 + 2] = fmaf(w, xv[2], acc[g * 4 + 2]);
                acc[g * 4 + 3] = fmaf(w, xv[3], acc[g * 4 + 3]);
            }
        }
    }

    const float b = bias[t];
    if (which < 2) {
        unsigned short* dst = (which == 0) ? Qb : Kb;
        const int h = t >> 5, d = t & 31;
        #pragma unroll
        for (int n = 0; n < 32; ++n)
            dst[((size_t)(h * NN + n0 + n)) * HD + d] = f2bf(acc[n] + b);
    } else {
        unsigned short* dst = Vtb + (size_t)t * NN + n0;
        #pragma unroll
        for (int g = 0; g < 4; ++g) {
            unsigned short v[8];
            #pragma unroll
            for (int k = 0; k < 8; ++k) v[k] = f2bf(acc[g * 8 + k] + b);
            *(bf16x8*)(void*)(dst + g * 8) = *(const bf16x8*)(const void*)v;
        }
    }
}

// ---------------------------------------------------------------------------
// Kernel 2: flash attention, fixed-max softmax, split-K x2.
// grid = (64 q-tiles, 8 heads, 2 k-splits); block = 256 thr = 4 waves.
// Wave owns 16 q-rows; per 32-key j-tile: 2 S-MFMAs, p=exp2(s-M) (no max
// tracking), P->LDS->A-frag (per-wave waitcnt), 2 PV-MFMAs.
// Emits UNNORMALIZED bf16 O-partial att[ks][o][n], fp32 l-partial lp[ks][h][n].
// ---------------------------------------------------------------------------
__global__ __launch_bounds__(256) void flash_kernel(
    const unsigned short* __restrict__ Q,
    const unsigned short* __restrict__ K,
    const unsigned short* __restrict__ Vt,
    const int* __restrict__ mask,
    unsigned short* __restrict__ att,
    float* __restrict__ lp)
{
    const int tid  = threadIdx.x;
    const int wave = tid >> 6;
    const int lane = tid & 63;
    const int quad = lane >> 4;
    const int l16  = lane & 15;
    const int h    = blockIdx.y;
    const int ks   = blockIdx.z;
    const int q0   = blockIdx.x * 64 + wave * 16;

    unsigned short* attp = att + (size_t)ks * CC * NN;
    float*          lpp  = lp  + (size_t)ks * NH * NN;

    // per-wave P buffer: 16 rows x 40 shorts (80B rows, 16B-aligned)
    __shared__ __align__(16) unsigned short plds[4][16 * 40];
    unsigned short* pw = plds[wave];

    // Q A-fragment: A[m=l16][k=quad*8+j]
    const bf16x8 aq =
        *(const bf16x8*)(const void*)(Q + ((size_t)(h * NN + q0 + l16)) * HD + quad * 8);

    const unsigned short* kbase = K + (size_t)h * NN * HD;
    const unsigned short* vb0p  = Vt + ((size_t)(h * HD + l16)) * NN;   // d = l16
    const unsigned short* vb1p  = vb0p + (size_t)16 * NN;               // d = 16+l16

    const int* mrow[4];
    #pragma unroll
    for (int r = 0; r < 4; ++r)
        mrow[r] = mask + ((size_t)(h * NN + q0 + quad * 4 + r)) * NN + l16;

    f32x4 O0 = {0.f, 0.f, 0.f, 0.f};
    f32x4 O1 = {0.f, 0.f, 0.f, 0.f};
    float l_[4] = {0.f, 0.f, 0.f, 0.f};

    // p = exp2(s*scale*log2e - M*log2e); M=8 (scores ~N(0,1), max ~5.7)
    const float cs = 0.25503372600239960f;   // (1/sqrt(32)) * log2(e)
    const float c8 = 11.541560327111707f;    // 8 * log2(e)
    const f32x4 zero4 = {0.f, 0.f, 0.f, 0.f};

    const int kbeg = ks * (NN / KSPLIT);
    const int kend = kbeg + (NN / KSPLIT);

    #pragma unroll 2
    for (int j0 = kbeg; j0 < kend; j0 += 32) {
        // K B-frags: lane reads K[j0+l16][quad*8..+8] (wave covers 1KB contig)
        bf16x8 bk0 = *(const bf16x8*)(const void*)(kbase + (size_t)(j0 + l16) * HD + quad * 8);
        bf16x8 bk1 = *(const bf16x8*)(const void*)(kbase + (size_t)(j0 + 16 + l16) * HD + quad * 8);
        // V B-frags: lane reads Vt[d][j0+quad*8..+8]
        bf16x8 bv0 = *(const bf16x8*)(const void*)(vb0p + j0 + quad * 8);
        bf16x8 bv1 = *(const bf16x8*)(const void*)(vb1p + j0 + quad * 8);
        // mask: 8 coalesced dwords/lane-iter (64B per quad-row)
        int mk0[4], mk1[4];
        #pragma unroll
        for (int r = 0; r < 4; ++r) { mk0[r] = mrow[r][j0]; mk1[r] = mrow[r][j0 + 16]; }

        f32x4 S0 = __builtin_amdgcn_mfma_f32_16x16x32_bf16(aq, bk0, zero4, 0, 0, 0);
        f32x4 S1 = __builtin_amdgcn_mfma_f32_16x16x32_bf16(aq, bk1, zero4, 0, 0, 0);

        #pragma unroll
        for (int r = 0; r < 4; ++r) {
            float t0 = S0[r] * cs - c8;  if (!mk0[r]) t0 = -1e38f;
            float t1 = S1[r] * cs - c8;  if (!mk1[r]) t1 = -1e38f;
            const float p0 = exp2f(t0);   // masked -> exactly 0
            const float p1 = exp2f(t1);
            l_[r] += p0 + p1;
            // C/D layout: row = quad*4+r, col = l16 (frag0) / 16+l16 (frag1)
            pw[(quad * 4 + r) * 40 + l16]      = f2bf(p0);
            pw[(quad * 4 + r) * 40 + 16 + l16] = f2bf(p1);
        }

        // same-wave LDS RAW: drain this wave's ds_writes before A-frag read
        __asm__ volatile("s_waitcnt lgkmcnt(0)" ::: "memory");
        bf16x8 ap = *(const bf16x8*)(const void*)(pw + l16 * 40 + quad * 8);

        O0 = __builtin_amdgcn_mfma_f32_16x16x32_bf16(ap, bv0, O0, 0, 0, 0);
        O1 = __builtin_amdgcn_mfma_f32_16x16x32_bf16(ap, bv1, O1, 0, 0, 0);
        // cross-iter WAR is same-wave only (per-wave buffer): DS in-order.
    }

    // deferred l reduction: sum across the 16 lanes of each quad group
    #pragma unroll
    for (int r = 0; r < 4; ++r) {
        float l = l_[r];
        l += __shfl_xor(l, 1);
        l += __shfl_xor(l, 2);
        l += __shfl_xor(l, 4);
        l += __shfl_xor(l, 8);
        const int n = q0 + quad * 4 + r;
        attp[(size_t)(h * HD + l16) * NN + n]      = f2bf(O0[r]);
        attp[(size_t)(h * HD + 16 + l16) * NN + n] = f2bf(O1[r]);
        if (l16 == 0) lpp[h * NN + n] = l;
    }
}

// ---------------------------------------------------------------------------
// Kernel 3: combine split-K partials, out = Wo@att + bo; z = x + out;
// channel LayerNorm per pixel. grid = 256 x 16-pixel tiles; thread = channel.
// ---------------------------------------------------------------------------
__global__ __launch_bounds__(256) void outln_kernel(
    const unsigned short* __restrict__ att,
    const float* __restrict__ lp,
    const float* __restrict__ x,
    const float* __restrict__ Wo,
    const float* __restrict__ bo,
    const float* __restrict__ gamma,
    const float* __restrict__ beta,
    float* __restrict__ out)
{
    const int t  = threadIdx.x;
    const int n0 = blockIdx.x * 16;

    __shared__ float as_[CC][20];
    __shared__ float red[2][16][16];
    __shared__ float mus[16], rstds[16];
    __shared__ float linv[NH][16];

    if (t < NH * 16) {
        const int h = t >> 4, nl = t & 15;
        float L = 0.f;
        #pragma unroll
        for (int s = 0; s < KSPLIT; ++s)
            L += lp[(size_t)s * NH * NN + h * NN + n0 + nl];
        linv[h][nl] = 1.f / fmaxf(L, 1e-20f);
    }
    __syncthreads();

    {
        const int h = t >> 5;
        #pragma unroll
        for (int g = 0; g < 2; ++g) {          // two ushort8 = 16 bf16
            float v[8] = {0.f,0.f,0.f,0.f,0.f,0.f,0.f,0.f};
            #pragma unroll
            for (int s = 0; s < KSPLIT; ++s) {
                ushort8 vs = *(const ushort8*)(const void*)
                    (att + (size_t)s * CC * NN + (size_t)t * NN + n0 + g * 8);
                #pragma unroll
                for (int k = 0; k < 8; ++k) v[k] += bf2f(vs[k]);
            }
            #pragma unroll
            for (int k = 0; k < 8; ++k)
                as_[t][g * 8 + k] = v[k] * linv[h][g * 8 + k];
        }
    }
    __syncthreads();

    float acc[16];
    #pragma unroll
    for (int i = 0; i < 16; ++i) acc[i] = 0.f;

    const float4v* w4p = (const float4v*)(Wo + (size_t)t * CC);
    for (int cg = 0; cg < 64; ++cg) {
        float4v w4 = w4p[cg];
        #pragma unroll
        for (int k = 0; k < 4; ++k) {
            const float w = w4[k];
            const float* xr = &as_[cg * 4 + k][0];
            #pragma unroll
            for (int g = 0; g < 4; ++g) {
                float4v xv = *(const float4v*)(xr + g * 4);
                acc[g * 4 + 0] = fmaf(w, xv[0], acc[g * 4 + 0]);
                acc[g * 4 + 1] = fmaf(w, xv[1], acc[g * 4 + 1]);
                acc[g * 4 + 2] = fmaf(w, xv[2], acc[g * 4 + 2]);
                acc[g * 4 + 3] = fmaf(w, xv[3], acc[g * 4 + 3]);
            }
        }
    }

    {
        const float b = bo[t];
        const float* xr = x + (size_t)t * NN + n0;
        #pragma unroll
        for (int g = 0; g < 4; ++g) {
            float4v xv = *(const float4v*)(xr + g * 4);
            acc[g * 4 + 0] += b + xv[0];
            acc[g * 4 + 1] += b + xv[1];
            acc[g * 4 + 2] += b + xv[2];
            acc[g * 4 + 3] += b + xv[3];
        }
    }

    __syncthreads();
    #pragma unroll
    for (int g = 0; g < 4; ++g) {
        float4v v = {acc[g * 4 + 0], acc[g * 4 + 1], acc[g * 4 + 2], acc[g * 4 + 3]};
        *(float4v*)&as_[t][g * 4] = v;
    }
    __syncthreads();

    {
        const int part = t >> 4, p = t & 15;
        float sm = 0.f, sq = 0.f;
        #pragma unroll
        for (int s = 0; s < 16; ++s) {
            float z = as_[part * 16 + s][p];
            sm += z;
            sq = fmaf(z, z, sq);
        }
        red[0][part][p] = sm;
        red[1][part][p] = sq;
    }
    __syncthreads();
    if (t < 16) {
        float S = 0.f, Q2 = 0.f;
        #pragma unroll
        for (int s = 0; s < 16; ++s) { S += red[0][s][t]; Q2 += red[1][s][t]; }
        const float mu  = S * (1.f / 256.f);
        const float var = Q2 * (1.f / 256.f) - mu * mu;
        mus[t]   = mu;
        rstds[t] = rsqrtf(fmaxf(var, 0.f) + 1e-5f);
    }
    __syncthreads();

    const float g_ = gamma[t];
    const float be = beta[t];
    float* dst = out + (size_t)t * NN + n0;
    #pragma unroll
    for (int g = 0; g < 4; ++g) {
        float4v v;
        v[0] = (acc[g * 4 + 0] - mus[g * 4 + 0]) * rstds[g * 4 + 0] * g_ + be;
        v[1] = (acc[g * 4 + 1] - mus[g * 4 + 1]) * rstds[g * 4 + 1] * g_ + be;
        v[2] = (acc[g * 4 + 2] - mus[g * 4 + 2]) * rstds[g * 4 + 2] * g_ + be;
        v[3] = (acc[g * 4 + 3] - mus[g * 4 + 3]) * rstds[g * 4 + 3] * g_ + be;
        *(float4v*)(dst + g * 4) = v;
    }
}

// ---------------------------------------------------------------------------
extern "C" void kernel_launch(void* const* d_in, const int* in_sizes, int n_in,
                              void* d_out, int out_size, void* d_ws, size_t ws_size,
                              hipStream_t stream) {
    const float* x     = (const float*)d_in[0];
    const int*   mask  = (const int*)d_in[1];
    const float* Wq    = (const float*)d_in[2];
    const float* bq    = (const float*)d_in[3];
    const float* Wk    = (const float*)d_in[4];
    const float* bk    = (const float*)d_in[5];
    const float* Wv    = (const float*)d_in[6];
    const float* bv    = (const float*)d_in[7];
    const float* Wo    = (const float*)d_in[8];
    const float* bo    = (const float*)d_in[9];
    const float* gamma = (const float*)d_in[10];
    const float* beta  = (const float*)d_in[11];

    // ws: Qb 2MB | Kb 2MB | Vtb 2MB | att bf16 2x2MB | lp 2x128KB  (~10.3MB)
    char* ws = (char*)d_ws;
    unsigned short* Qb  = (unsigned short*)ws;
    unsigned short* Kb  = Qb + (size_t)NH * NN * HD;
    unsigned short* Vtb = Kb + (size_t)NH * NN * HD;
    unsigned short* att = Vtb + (size_t)NH * NN * HD;
    float*          lpt = (float*)(att + (size_t)KSPLIT * CC * NN);

    proj_kernel<<<dim3(NN / 32, 3), 256, 0, stream>>>(x, Wq, bq, Wk, bk, Wv, bv,
                                                      Qb, Kb, Vtb);
    flash_kernel<<<dim3(NN / 64, NH, KSPLIT), 256, 0, stream>>>(Qb, Kb, Vtb,
                                                                mask, att, lpt);
    outln_kernel<<<dim3(NN / 16), 256, 0, stream>>>(att, lpt, x, Wo, bo,
                                                    gamma, beta, (float*)d_out);
}